// Round 6
// baseline (1246.748 us; speedup 1.0000x reference)
//
#include <hip/hip_runtime.h>

// APPNP: h = relu(x@W0+b0)@W1+b1 ; z0=h ; z_{k+1} = 0.9 * (Ahat z_k) + 0.1 * h  (10 iters)
// Ahat = D^-1/2 (A + I) D^-1/2, deg by source(row) incl. self-loop weight 1.
//
// R2: device-scope atomics eliminated (paged LDS hist). R3: grid starvation fixed.
// R4: BPP 64; k_prop unroll 8. R5: srcw packed 4B/edge; h bf16-only; predicated prop.
// R7 FAILED: MFMA mlp, direct-global A-frags latency-dead (16 rows x 2048B stride
//     per load = single L1 set; MfmaUtil 5%). R8/R9 FAILED worse (202us, all pipes
//     idle): LDS staging kept the same 16-rows-per-instruction stage map (same L1
//     single-set alias, serialized MSHR misses) and added vmcnt(0)+barrier drains.
// R10: fix the stage ACCESS PATTERN + hide latency:
//     (a) wave-contiguous stage: instr i reads rows i*8+(tid>>5), col (tid&31)*4
//         -> 64 lanes x 16B fully coalesced, 2 contiguous 512B segments per wave,
//         8 L1 sets per row instead of 16 rows in one set.
//     (b) register prefetch dbuf (T14 issue-early/write-late): chunk kc+1's loads
//         issue before chunk kc's convert+consume; latency hides under ~1000cy of
//         convert/barrier/MFMA. LDS single-buffered 34.8KB -> 4 blocks/CU.
//     Convert math byte-identical to R8 (trunc-hi + rne-lo, proven absmax).

#define PAGE 16128 // dests per page; 16128*4B = 63KB LDS histogram -> 2 blocks/CU
#define BPP 64     // blocks per page (each scans E/BPP edge chunk)
#define XST 136    // LDS row stride (u16): 128 + 8 pad -> 2-way bank alias only

typedef __attribute__((ext_vector_type(8))) short bf16x8;
typedef __attribute__((ext_vector_type(4))) float f32x4;

// ---- bf16 helpers ----
__device__ __forceinline__ float bf_lo(unsigned z) { return __uint_as_float(z << 16); }
__device__ __forceinline__ float bf_hi(unsigned z) { return __uint_as_float(z & 0xffff0000u); }
__device__ __forceinline__ unsigned bf_rne(float x) {
    unsigned u = __float_as_uint(x);
    return (u + 0x7fffu + ((u >> 16) & 1u)) >> 16;
}
__device__ __forceinline__ unsigned bf_pack(float x, float y) { return bf_rne(x) | (bf_rne(y) << 16); }

// ---- deg histogram by row (float, weighted), paged ----
__global__ __launch_bounds__(256) void k_deg(const int* __restrict__ row, const float* __restrict__ ew,
                                             float* __restrict__ slab, int E, int chunk) {
    __shared__ float hf[PAGE];
    int p = blockIdx.x / BPP, b = blockIdx.x - p * BPP;
    int lo = p * PAGE;
    for (int i = threadIdx.x; i < PAGE; i += 256) hf[i] = 0.f;
    __syncthreads();
    int e0 = b * chunk, e1 = min(e0 + chunk, E);
    int evec = e0 + ((e1 - e0) & ~3);
    for (int e = e0 + (int)threadIdx.x * 4; e + 4 <= evec; e += 1024) {
        int4 r4 = *(const int4*)(row + e);
        float4 w4 = *(const float4*)(ew + e);
        unsigned a = (unsigned)(r4.x - lo), bq = (unsigned)(r4.y - lo);
        unsigned c = (unsigned)(r4.z - lo), dq = (unsigned)(r4.w - lo);
        if (a < PAGE) atomicAdd(&hf[a], w4.x);
        if (bq < PAGE) atomicAdd(&hf[bq], w4.y);
        if (c < PAGE) atomicAdd(&hf[c], w4.z);
        if (dq < PAGE) atomicAdd(&hf[dq], w4.w);
    }
    for (int e = evec + (int)threadIdx.x; e < e1; e += 256) {
        unsigned a = (unsigned)(row[e] - lo);
        if (a < PAGE) atomicAdd(&hf[a], ew[e]);
    }
    __syncthreads();
    float* out = slab + (size_t)blockIdx.x * PAGE;
    for (int i = threadIdx.x; i < PAGE; i += 256) out[i] = hf[i];
}

__global__ __launch_bounds__(256) void k_fold_deg(const float* __restrict__ slab, float* __restrict__ dinv, int N) {
    int i = blockIdx.x * 256 + threadIdx.x;
    if (i >= N) return;
    int p = i / PAGE, ld = i - p * PAGE;
    const float* base = slab + (size_t)(p * BPP) * PAGE + ld;
    float d = 1.0f;  // self-loop weight
#pragma unroll
    for (int b = 0; b < BPP; ++b) d += base[(size_t)b * PAGE];
    dinv[i] = d > 0.f ? rsqrtf(d) : 0.f;
}

// ---- cnt histogram by col (u16 slab), paged ----
__global__ __launch_bounds__(256) void k_cnt(const int* __restrict__ col, unsigned short* __restrict__ slab,
                                             int E, int chunk) {
    __shared__ int hi[PAGE];
    int p = blockIdx.x / BPP, b = blockIdx.x - p * BPP;
    int lo = p * PAGE;
    for (int i = threadIdx.x; i < PAGE; i += 256) hi[i] = 0;
    __syncthreads();
    int e0 = b * chunk, e1 = min(e0 + chunk, E);
    int evec = e0 + ((e1 - e0) & ~3);
    for (int e = e0 + (int)threadIdx.x * 4; e + 4 <= evec; e += 1024) {
        int4 c4 = *(const int4*)(col + e);
        unsigned a = (unsigned)(c4.x - lo), bq = (unsigned)(c4.y - lo);
        unsigned c = (unsigned)(c4.z - lo), dq = (unsigned)(c4.w - lo);
        if (a < PAGE) atomicAdd(&hi[a], 1);
        if (bq < PAGE) atomicAdd(&hi[bq], 1);
        if (c < PAGE) atomicAdd(&hi[c], 1);
        if (dq < PAGE) atomicAdd(&hi[dq], 1);
    }
    for (int e = evec + (int)threadIdx.x; e < e1; e += 256) {
        unsigned a = (unsigned)(col[e] - lo);
        if (a < PAGE) atomicAdd(&hi[a], 1);
    }
    __syncthreads();
    unsigned short* out = slab + (size_t)blockIdx.x * PAGE;
    for (int i = threadIdx.x; i < PAGE; i += 256) out[i] = (unsigned short)hi[i];
}

// fold cnt: total per dest + per-block exclusive offsets written back in place (u16)
__global__ __launch_bounds__(256) void k_fold_cnt(unsigned short* __restrict__ slab, int* __restrict__ cnt, int N) {
    int i = blockIdx.x * 256 + threadIdx.x;
    if (i >= N) return;
    int p = i / PAGE, ld = i - p * PAGE;
    unsigned short* base = slab + (size_t)(p * BPP) * PAGE + ld;
    int run = 0;
#pragma unroll
    for (int b = 0; b < BPP; ++b) {
        size_t off = (size_t)b * PAGE;
        int v = base[off];
        base[off] = (unsigned short)run;
        run += v;
    }
    cnt[i] = run;
}

// ---- 3-kernel exclusive scan of cnt[N] -> rowp[N], chunk = 1024 ----
__global__ __launch_bounds__(256) void k_scanA(const int* __restrict__ cnt, int* __restrict__ csum, int N) {
    __shared__ int s[256];
    int t = threadIdx.x, base = blockIdx.x * 1024;
    int p = 0;
#pragma unroll
    for (int j = 0; j < 4; ++j) { int idx = base + t + 256 * j; if (idx < N) p += cnt[idx]; }
    s[t] = p; __syncthreads();
    for (int off = 128; off > 0; off >>= 1) { if (t < off) s[t] += s[t + off]; __syncthreads(); }
    if (t == 0) csum[blockIdx.x] = s[0];
}

__global__ __launch_bounds__(256) void k_scanB(int* __restrict__ csum, int NC) {
    __shared__ int s[256];
    int t = threadIdx.x;
    int v = (t < NC) ? csum[t] : 0;
    s[t] = v; __syncthreads();
    for (int off = 1; off < 256; off <<= 1) {
        int x = (t >= off) ? s[t - off] : 0;
        __syncthreads();
        s[t] += x; __syncthreads();
    }
    if (t < NC) csum[t] = s[t] - v;  // exclusive
}

__global__ __launch_bounds__(256) void k_scanC(const int* __restrict__ cnt, const int* __restrict__ csum,
                                               int* __restrict__ rowp, int N) {
    __shared__ int s[256];
    int t = threadIdx.x, base = blockIdx.x * 1024 + t * 4;
    int c0 = (base + 0 < N) ? cnt[base + 0] : 0;
    int c1 = (base + 1 < N) ? cnt[base + 1] : 0;
    int c2 = (base + 2 < N) ? cnt[base + 2] : 0;
    int c3 = (base + 3 < N) ? cnt[base + 3] : 0;
    int ts = c0 + c1 + c2 + c3;
    s[t] = ts; __syncthreads();
    for (int off = 1; off < 256; off <<= 1) {
        int x = (t >= off) ? s[t - off] : 0;
        __syncthreads();
        s[t] += x; __syncthreads();
    }
    int o = csum[blockIdx.x] + s[t] - ts;
    if (base + 0 < N) rowp[base + 0] = o;
    if (base + 1 < N) rowp[base + 1] = o + c0;
    if (base + 2 < N) rowp[base + 2] = o + c0 + c1;
    if (base + 3 < N) rowp[base + 3] = o + c0 + c1 + c2;
}

// ---- scatter: deterministic positions, LDS cursors only; packed 4B payload ----
// payload = (src << 15) | (bf16(dinv[src]*ew) & 0x7fff)   [w >= 0, src < 2^17]
__global__ __launch_bounds__(256) void k_scat(const int* __restrict__ row, const int* __restrict__ col,
                                              const float* __restrict__ ew, const float* __restrict__ dinv,
                                              const int* __restrict__ rowp, const unsigned short* __restrict__ slab,
                                              unsigned* __restrict__ srcw, int E, int chunk) {
    __shared__ int cur[PAGE];
    int p = blockIdx.x / BPP, b = blockIdx.x - p * BPP;
    int lo = p * PAGE;
    for (int i = threadIdx.x; i < PAGE; i += 256) cur[i] = 0;
    __syncthreads();
    const unsigned short* soff = slab + (size_t)blockIdx.x * PAGE;
    int e0 = b * chunk, e1 = min(e0 + chunk, E);
    int evec = e0 + ((e1 - e0) & ~3);
    for (int e = e0 + (int)threadIdx.x * 4; e + 4 <= evec; e += 1024) {
        int4 c4 = *(const int4*)(col + e);
        unsigned a = (unsigned)(c4.x - lo), bq = (unsigned)(c4.y - lo);
        unsigned cc = (unsigned)(c4.z - lo), dq = (unsigned)(c4.w - lo);
        if ((a < PAGE) | (bq < PAGE) | (cc < PAGE) | (dq < PAGE)) {
            int4 r4 = *(const int4*)(row + e);
            float4 w4 = *(const float4*)(ew + e);
            if (a < PAGE) {
                int pos = rowp[c4.x] + soff[a] + atomicAdd(&cur[a], 1);
                srcw[pos] = ((unsigned)r4.x << 15) | (bf_rne(dinv[r4.x] * w4.x) & 0x7fffu);
            }
            if (bq < PAGE) {
                int pos = rowp[c4.y] + soff[bq] + atomicAdd(&cur[bq], 1);
                srcw[pos] = ((unsigned)r4.y << 15) | (bf_rne(dinv[r4.y] * w4.y) & 0x7fffu);
            }
            if (cc < PAGE) {
                int pos = rowp[c4.z] + soff[cc] + atomicAdd(&cur[cc], 1);
                srcw[pos] = ((unsigned)r4.z << 15) | (bf_rne(dinv[r4.z] * w4.z) & 0x7fffu);
            }
            if (dq < PAGE) {
                int pos = rowp[c4.w] + soff[dq] + atomicAdd(&cur[dq], 1);
                srcw[pos] = ((unsigned)r4.w << 15) | (bf_rne(dinv[r4.w] * w4.w) & 0x7fffu);
            }
        }
    }
    for (int e = evec + (int)threadIdx.x; e < e1; e += 256) {
        int c = col[e];
        unsigned a = (unsigned)(c - lo);
        if (a < PAGE) {
            int r = row[e];
            int pos = rowp[c] + soff[a] + atomicAdd(&cur[a], 1);
            srcw[pos] = ((unsigned)r << 15) | (bf_rne(dinv[r] * ew[e]) & 0x7fffu);
        }
    }
}

// ---- weight transpose + bf16 hi/lo split (both layers in one launch) ----
// i < 512*64: W0[K=512][64] -> Th0/Tl0[64][512]; else W1[64][64] -> Th1/Tl1[64][64]
__global__ __launch_bounds__(256) void k_wcvt(const float* __restrict__ W0, const float* __restrict__ W1,
                                              unsigned short* __restrict__ Th0, unsigned short* __restrict__ Tl0,
                                              unsigned short* __restrict__ Th1, unsigned short* __restrict__ Tl1) {
    int i = blockIdx.x * 256 + threadIdx.x;
    float v;
    unsigned short *th, *tl;
    size_t o;
    if (i < 512 * 64) {
        int k = i >> 6, n = i & 63;
        v = W0[i];
        th = Th0; tl = Tl0; o = (size_t)n * 512 + k;
    } else {
        int j = i - 512 * 64;
        if (j >= 64 * 64) return;
        int k = j >> 6, n = j & 63;
        v = W1[j];
        th = Th1; tl = Tl1; o = (size_t)n * 64 + k;
    }
    unsigned hi = bf_rne(v);
    float hv = __uint_as_float(hi << 16);
    unsigned lo = bf_rne(v - hv);
    th[o] = (unsigned short)hi;
    tl[o] = (unsigned short)lo;
}

// ---- MFMA 2-layer MLP: 64 rows/block, 4 waves, bf16 hi/lo split, prefetch dbuf ----
// Stage map (R10): instr i covers rows i*8+(tid>>5), col-float4 (tid&31) -> each wave
// reads 2 contiguous 512B row-segments (full 64x16B coalescing, 8 L1 sets/row).
// A-frags via ds_read_b128 from padded LDS; W^T hi/lo from global (256KB L2-hot).
// D-frag: col = lane&15, row = 4*(lane>>4) + reg  [HW-verified].
__global__ __launch_bounds__(256, 4) void k_mlp(const float* __restrict__ x,
                                                const unsigned short* __restrict__ w0th, const unsigned short* __restrict__ w0tl,
                                                const unsigned short* __restrict__ w1th, const unsigned short* __restrict__ w1tl,
                                                const float* __restrict__ b0, const float* __restrict__ b1,
                                                unsigned* __restrict__ hb, int N) {
    __shared__ __align__(16) unsigned short xh[64 * XST];  // 17.4 KB: chunk A hi; layer-1 out reuses
    __shared__ __align__(16) unsigned short xl[64 * XST];  // 17.4 KB: chunk A lo
    int tid = threadIdx.x;
    int w = tid >> 6, lane = tid & 63;
    int g = lane >> 4, r16 = lane & 15;
    int rbase = blockIdx.x * 64;

    // R10 stage map: per instr i, row = i*8 + r8, col-float4 = c4 (wave-contiguous)
    int r8 = tid >> 5;   // 0..7
    int c4 = tid & 31;   // 0..31
    const float* xbase = x + (size_t)(rbase + r8) * 512 + c4 * 4;

    auto LOADX = [&](float4 (&v)[8], int kc) {
#pragma unroll
        for (int i = 0; i < 8; ++i)
            v[i] = (rbase + i * 8 + r8 < N)
                       ? *(const float4*)(xbase + (size_t)i * 4096 + kc * 128)
                       : make_float4(0.f, 0.f, 0.f, 0.f);
    };
    auto CWRITE = [&](float4 (&v)[8]) {
#pragma unroll
        for (int i = 0; i < 8; ++i) {
            float e0 = v[i].x, e1 = v[i].y, e2 = v[i].z, e3 = v[i].w;
            unsigned u0 = __float_as_uint(e0), u1 = __float_as_uint(e1);
            unsigned u2 = __float_as_uint(e2), u3 = __float_as_uint(e3);
            // hi = truncate to bf16 (exact prefix), lo = rne(x - hi)
            unsigned short h0 = (unsigned short)(u0 >> 16), h1q = (unsigned short)(u1 >> 16);
            unsigned short h2 = (unsigned short)(u2 >> 16), h3 = (unsigned short)(u3 >> 16);
            float l0 = e0 - __uint_as_float(u0 & 0xffff0000u);
            float l1 = e1 - __uint_as_float(u1 & 0xffff0000u);
            float l2 = e2 - __uint_as_float(u2 & 0xffff0000u);
            float l3 = e3 - __uint_as_float(u3 & 0xffff0000u);
            int o = (i * 8 + r8) * XST + c4 * 4;
            ushort4 hv4 = make_ushort4(h0, h1q, h2, h3);
            ushort4 lv4 = make_ushort4((unsigned short)bf_rne(l0), (unsigned short)bf_rne(l1),
                                       (unsigned short)bf_rne(l2), (unsigned short)bf_rne(l3));
            *(ushort4*)(xh + o) = hv4;
            *(ushort4*)(xl + o) = lv4;
        }
    };

    f32x4 acc[4];
#pragma unroll
    for (int t = 0; t < 4; ++t) acc[t] = (f32x4){0.f, 0.f, 0.f, 0.f};

    float4 va[8], vb[8];
    LOADX(va, 0);
#pragma unroll
    for (int kc = 0; kc < 4; ++kc) {  // 4 chunks of 128 k, reg-prefetch pipelined
        if (kc == 0) { if (0 < 3) LOADX(vb, 1); CWRITE(va); }
        else if (kc == 1) { LOADX(va, 2); CWRITE(vb); }
        else if (kc == 2) { LOADX(vb, 3); CWRITE(va); }
        else { CWRITE(vb); }
        __syncthreads();
        // ---- consume: 4 MFMA k-steps of 32 ----
#pragma unroll
        for (int ks = 0; ks < 4; ++ks) {
            int kk = ks * 32 + g * 8;
            bf16x8 ah = *(const bf16x8*)(xh + (w * 16 + r16) * XST + kk);
            bf16x8 al = *(const bf16x8*)(xl + (w * 16 + r16) * XST + kk);
            int kg = kc * 128 + kk;
#pragma unroll
            for (int t = 0; t < 4; ++t) {
                size_t wo = (size_t)(t * 16 + r16) * 512 + kg;
                bf16x8 wh = *(const bf16x8*)(w0th + wo);
                bf16x8 wl = *(const bf16x8*)(w0tl + wo);
                acc[t] = __builtin_amdgcn_mfma_f32_16x16x32_bf16(ah, wh, acc[t], 0, 0, 0);
                acc[t] = __builtin_amdgcn_mfma_f32_16x16x32_bf16(al, wh, acc[t], 0, 0, 0);
                acc[t] = __builtin_amdgcn_mfma_f32_16x16x32_bf16(ah, wl, acc[t], 0, 0, 0);
            }
        }
        __syncthreads();  // before next chunk's staging overwrites LDS
    }
    // ---- epilogue L1: +b0, relu, hi/lo split -> LDS (row-stride 72) ----
#pragma unroll
    for (int t = 0; t < 4; ++t) {
        int c = t * 16 + r16;
        float bb = b0[c];
#pragma unroll
        for (int r = 0; r < 4; ++r) {
            float vv = fmaxf(acc[t][r] + bb, 0.f);
            unsigned u = __float_as_uint(vv);
            unsigned short hi = (unsigned short)(u >> 16);
            float lo = vv - __uint_as_float(u & 0xffff0000u);
            int rr = w * 16 + g * 4 + r;
            xh[rr * 72 + c] = hi;
            xl[rr * 72 + c] = (unsigned short)bf_rne(lo);
        }
    }
    __syncthreads();
    // ---- layer 2: K = 64, 2 k-steps ----
    f32x4 acc2[4];
#pragma unroll
    for (int t = 0; t < 4; ++t) acc2[t] = (f32x4){0.f, 0.f, 0.f, 0.f};
#pragma unroll
    for (int ks = 0; ks < 2; ++ks) {
        int k0 = ks * 32 + g * 8;
        bf16x8 ah = *(const bf16x8*)(xh + (w * 16 + r16) * 72 + k0);
        bf16x8 al = *(const bf16x8*)(xl + (w * 16 + r16) * 72 + k0);
#pragma unroll
        for (int t = 0; t < 4; ++t) {
            size_t wo = (size_t)(t * 16 + r16) * 64 + k0;
            bf16x8 wh = *(const bf16x8*)(w1th + wo);
            bf16x8 wl = *(const bf16x8*)(w1tl + wo);
            acc2[t] = __builtin_amdgcn_mfma_f32_16x16x32_bf16(ah, wh, acc2[t], 0, 0, 0);
            acc2[t] = __builtin_amdgcn_mfma_f32_16x16x32_bf16(al, wh, acc2[t], 0, 0, 0);
            acc2[t] = __builtin_amdgcn_mfma_f32_16x16x32_bf16(ah, wl, acc2[t], 0, 0, 0);
        }
    }
    // ---- epilogue L2: +b1 -> bf16 u16 stores ----
    unsigned short* hb16 = (unsigned short*)hb;
#pragma unroll
    for (int t = 0; t < 4; ++t) {
        int c = t * 16 + r16;
        float bb = b1[c];
#pragma unroll
        for (int r = 0; r < 4; ++r) {
            int grow = rbase + w * 16 + g * 4 + r;
            if (grow < N) {
                float vv = acc2[t][r] + bb;
                hb16[(size_t)grow * 64 + c] = (unsigned short)bf_rne(vv);
            }
        }
    }
}

// ---- propagation: wave per dest, 2 edges x 32 lanes, bf16 z gather, predicated unroll 8 ----
// srcw packed 4B: src = pk>>15, w = bits((pk&0x7fff)<<16); agg scaled by dinv[d] in epilogue.
__global__ __launch_bounds__(256) void k_prop(const unsigned* __restrict__ srcw,
                                              const int* __restrict__ rowp, const int* __restrict__ cnt,
                                              const float* __restrict__ dinv,
                                              const unsigned* __restrict__ zin, const unsigned* __restrict__ hb,
                                              unsigned* __restrict__ zout_b, float* __restrict__ zout_f, int N) {
    int wid = (blockIdx.x << 2) | (threadIdx.x >> 6);
    int d = __builtin_amdgcn_readfirstlane(wid);  // wave-uniform -> scalar loads for per-dest data
    if (d >= N) return;
    int lane = threadIdx.x & 63;
    int half = lane >> 5, fi = lane & 31;  // lane handles features (2fi, 2fi+1) of edge parity `half`
    int beg = rowp[d], end = beg + cnt[d];
    float ax = 0.f, ay = 0.f;
    for (int e = beg + half; e < end; e += 16) {  // 8 edges per parity always in flight
        unsigned pk[8];
#pragma unroll
        for (int k = 0; k < 8; ++k) {
            int idx = e + 2 * k;
            pk[k] = srcw[min(idx, end - 1)];  // clamp: dead slots re-read last valid edge (L1-hot)
        }
        unsigned z[8];
#pragma unroll
        for (int k = 0; k < 8; ++k) z[k] = zin[(pk[k] >> 15) * 32u + fi];
#pragma unroll
        for (int k = 0; k < 8; ++k) {
            float w = (e + 2 * k < end) ? __uint_as_float((pk[k] & 0x7fffu) << 16) : 0.f;
            ax = fmaf(w, bf_lo(z[k]), ax);
            ay = fmaf(w, bf_hi(z[k]), ay);
        }
    }
    ax += __shfl_xor(ax, 32);
    ay += __shfl_xor(ay, 32);
    if (half == 0) {
        float di = dinv[d];
        unsigned zs = zin[(size_t)d * 32 + fi];  // analytic self-loop
        float s2 = di * di;
        float ox = 0.9f * fmaf(di, ax, s2 * bf_lo(zs));
        float oy = 0.9f * fmaf(di, ay, s2 * bf_hi(zs));
        unsigned hz = hb[(size_t)d * 32 + fi];
        ox = fmaf(0.1f, bf_lo(hz), ox);
        oy = fmaf(0.1f, bf_hi(hz), oy);
        if (zout_f) ((float2*)zout_f)[(size_t)d * 32 + fi] = make_float2(ox, oy);
        else zout_b[(size_t)d * 32 + fi] = bf_pack(ox, oy);
    }
}

extern "C" void kernel_launch(void* const* d_in, const int* in_sizes, int n_in,
                              void* d_out, int out_size, void* d_ws, size_t ws_size,
                              hipStream_t stream) {
    const float* x  = (const float*)d_in[0];
    const int*   ei = (const int*)d_in[1];
    const float* ew = (const float*)d_in[2];
    const float* W0 = (const float*)d_in[3];
    const float* b0 = (const float*)d_in[4];
    const float* W1 = (const float*)d_in[5];
    const float* b1 = (const float*)d_in[6];
    int N = in_sizes[0] / 512;
    int E = in_sizes[2];
    const int* row = ei;
    const int* col = ei + E;

    char* p = (char*)d_ws;
    auto alloc = [&](size_t bytes) -> char* {
        char* r = p;
        p += (bytes + 255) & ~(size_t)255;
        return r;
    };
    int NPg = (N + PAGE - 1) / PAGE;                         // 7 pages for N=100K
    size_t zbytes = (size_t)N * 32 * 4;                      // 12.8 MB per bf16 z buffer
    size_t slab_bytes = (size_t)NPg * BPP * PAGE * 4;        // 28.9 MB float deg slab (hosts u16 cnt slab too)
    unsigned* hb  = (unsigned*)alloc(zbytes);                // bf16 h, persists all iters
    float* slabf  = (float*)alloc(slab_bytes);               // dead after k_scat
    unsigned* srcw = (unsigned*)alloc((size_t)E * 4);        // 12.8 MB packed edges
    float* dinv  = (float*)alloc((size_t)N * 4);
    int* cnt     = (int*)alloc((size_t)N * 4);
    int* rowp    = (int*)alloc((size_t)N * 4);
    int* csum    = (int*)alloc(512 * 4);
    unsigned short* w0th = (unsigned short*)alloc(64 * 512 * 2);  // W0^T bf16 hi
    unsigned short* w0tl = (unsigned short*)alloc(64 * 512 * 2);  // W0^T bf16 lo
    unsigned short* w1th = (unsigned short*)alloc(64 * 64 * 2);   // W1^T bf16 hi
    unsigned short* w1tl = (unsigned short*)alloc(64 * 64 * 2);   // W1^T bf16 lo
    unsigned short* slabu = (unsigned short*)slabf;  // sequential reuse: deg fold before k_cnt writes
    // zb0/zb1 overlay the slab region (slab dead once k_scat finishes; stream order).
    unsigned* zb0 = (unsigned*)slabf;
    unsigned* zb1 = (unsigned*)((char*)slabf + zbytes);

    int gN = (N + 255) / 256;
    int NC = (N + 1023) / 1024;
    int chunk = (((E + BPP - 1) / BPP) + 3) & ~3;
    int gridPg = NPg * BPP;

    k_wcvt<<<(512 * 64 + 64 * 64 + 255) / 256, 256, 0, stream>>>(W0, W1, w0th, w0tl, w1th, w1tl);
    k_deg<<<gridPg, 256, 0, stream>>>(row, ew, slabf, E, chunk);
    k_fold_deg<<<gN, 256, 0, stream>>>(slabf, dinv, N);
    k_cnt<<<gridPg, 256, 0, stream>>>(col, slabu, E, chunk);
    k_fold_cnt<<<gN, 256, 0, stream>>>(slabu, cnt, N);
    k_scanA<<<NC, 256, 0, stream>>>(cnt, csum, N);
    k_scanB<<<1, 256, 0, stream>>>(csum, NC);
    k_scanC<<<NC, 256, 0, stream>>>(cnt, csum, rowp, N);
    k_scat<<<gridPg, 256, 0, stream>>>(row, col, ew, dinv, rowp, slabu, srcw, E, chunk);
    k_mlp<<<(N + 63) / 64, 256, 0, stream>>>(x, w0th, w0tl, w1th, w1tl, b0, b1, hb, N);

    unsigned* zbufs[2] = { zb0, zb1 };  // iter it writes zbufs[it&1] (bf16) except final
    const unsigned* zi = hb;            // z0 = bf16(h), no conversion kernel needed
    int gP = (N + 3) / 4;
    for (int it = 0; it < 10; ++it) {
        if (it < 9) {
            unsigned* zo = zbufs[it & 1];
            k_prop<<<gP, 256, 0, stream>>>(srcw, rowp, cnt, dinv, zi, hb, zo, nullptr, N);
            zi = zo;
        } else {
            k_prop<<<gP, 256, 0, stream>>>(srcw, rowp, cnt, dinv, zi, hb, nullptr, (float*)d_out, N);
        }
    }
}

// Round 7
// 1175.170 us; speedup vs baseline: 1.0609x; 1.0609x over previous
//
#include <hip/hip_runtime.h>

// APPNP: h = relu(x@W0+b0)@W1+b1 ; z0=h ; z_{k+1} = 0.9 * (Ahat z_k) + 0.1 * h  (10 iters)
// Ahat = D^-1/2 (A + I) D^-1/2, deg by source(row) incl. self-loop weight 1.
//
// R2: device-scope atomics eliminated (paged LDS hist). R3: grid starvation fixed.
// R4: BPP 64; k_prop unroll 8. R5: srcw packed 4B/edge; h bf16-only; predicated prop.
// R7-R10 FAILED (168/202/221us, all pipes idle): every MFMA variant kept B-frag
//     (W^T) loads reading 16 rows x 1024B stride per instruction -> 16 lines in 2
//     L1 sets -> self-thrashing, serialized on the CU's shared L1 pipeline. The
//     A-path fixes (R8 LDS stage, R10 coalesced stage map) never touched it.
//     R10's reg-dbuf also spilled (VGPR 64 cap, WRITE_SIZE +4.7MB scratch).
// R11: pre-pack W into MFMA FRAGMENT ORDER (k_wcvt): F[frag][sel][lane][8] u16 so
//     each consume W-load is base+lane*16B -- one contiguous coalesced 1KB per
//     instruction, same stream for all 4 waves (L1-hot, 32KB/chunk). Same
//     (lane,elem)->(col,k) map as R7-R10 (math verified, absmax 0.015625);
//     memory layout only. Dropped spilling reg-dbuf (4 blocks/CU TLP hides x).

#define PAGE 16128 // dests per page; 16128*4B = 63KB LDS histogram -> 2 blocks/CU
#define BPP 64     // blocks per page (each scans E/BPP edge chunk)
#define XST 136    // LDS row stride (u16): 128 + 8 pad -> 2-way bank alias only

typedef __attribute__((ext_vector_type(8))) short bf16x8;
typedef __attribute__((ext_vector_type(4))) float f32x4;

// ---- bf16 helpers ----
__device__ __forceinline__ float bf_lo(unsigned z) { return __uint_as_float(z << 16); }
__device__ __forceinline__ float bf_hi(unsigned z) { return __uint_as_float(z & 0xffff0000u); }
__device__ __forceinline__ unsigned bf_rne(float x) {
    unsigned u = __float_as_uint(x);
    return (u + 0x7fffu + ((u >> 16) & 1u)) >> 16;
}
__device__ __forceinline__ unsigned bf_pack(float x, float y) { return bf_rne(x) | (bf_rne(y) << 16); }

// ---- deg histogram by row (float, weighted), paged ----
__global__ __launch_bounds__(256) void k_deg(const int* __restrict__ row, const float* __restrict__ ew,
                                             float* __restrict__ slab, int E, int chunk) {
    __shared__ float hf[PAGE];
    int p = blockIdx.x / BPP, b = blockIdx.x - p * BPP;
    int lo = p * PAGE;
    for (int i = threadIdx.x; i < PAGE; i += 256) hf[i] = 0.f;
    __syncthreads();
    int e0 = b * chunk, e1 = min(e0 + chunk, E);
    int evec = e0 + ((e1 - e0) & ~3);
    for (int e = e0 + (int)threadIdx.x * 4; e + 4 <= evec; e += 1024) {
        int4 r4 = *(const int4*)(row + e);
        float4 w4 = *(const float4*)(ew + e);
        unsigned a = (unsigned)(r4.x - lo), bq = (unsigned)(r4.y - lo);
        unsigned c = (unsigned)(r4.z - lo), dq = (unsigned)(r4.w - lo);
        if (a < PAGE) atomicAdd(&hf[a], w4.x);
        if (bq < PAGE) atomicAdd(&hf[bq], w4.y);
        if (c < PAGE) atomicAdd(&hf[c], w4.z);
        if (dq < PAGE) atomicAdd(&hf[dq], w4.w);
    }
    for (int e = evec + (int)threadIdx.x; e < e1; e += 256) {
        unsigned a = (unsigned)(row[e] - lo);
        if (a < PAGE) atomicAdd(&hf[a], ew[e]);
    }
    __syncthreads();
    float* out = slab + (size_t)blockIdx.x * PAGE;
    for (int i = threadIdx.x; i < PAGE; i += 256) out[i] = hf[i];
}

__global__ __launch_bounds__(256) void k_fold_deg(const float* __restrict__ slab, float* __restrict__ dinv, int N) {
    int i = blockIdx.x * 256 + threadIdx.x;
    if (i >= N) return;
    int p = i / PAGE, ld = i - p * PAGE;
    const float* base = slab + (size_t)(p * BPP) * PAGE + ld;
    float d = 1.0f;  // self-loop weight
#pragma unroll
    for (int b = 0; b < BPP; ++b) d += base[(size_t)b * PAGE];
    dinv[i] = d > 0.f ? rsqrtf(d) : 0.f;
}

// ---- cnt histogram by col (u16 slab), paged ----
__global__ __launch_bounds__(256) void k_cnt(const int* __restrict__ col, unsigned short* __restrict__ slab,
                                             int E, int chunk) {
    __shared__ int hi[PAGE];
    int p = blockIdx.x / BPP, b = blockIdx.x - p * BPP;
    int lo = p * PAGE;
    for (int i = threadIdx.x; i < PAGE; i += 256) hi[i] = 0;
    __syncthreads();
    int e0 = b * chunk, e1 = min(e0 + chunk, E);
    int evec = e0 + ((e1 - e0) & ~3);
    for (int e = e0 + (int)threadIdx.x * 4; e + 4 <= evec; e += 1024) {
        int4 c4 = *(const int4*)(col + e);
        unsigned a = (unsigned)(c4.x - lo), bq = (unsigned)(c4.y - lo);
        unsigned c = (unsigned)(c4.z - lo), dq = (unsigned)(c4.w - lo);
        if (a < PAGE) atomicAdd(&hi[a], 1);
        if (bq < PAGE) atomicAdd(&hi[bq], 1);
        if (c < PAGE) atomicAdd(&hi[c], 1);
        if (dq < PAGE) atomicAdd(&hi[dq], 1);
    }
    for (int e = evec + (int)threadIdx.x; e < e1; e += 256) {
        unsigned a = (unsigned)(col[e] - lo);
        if (a < PAGE) atomicAdd(&hi[a], 1);
    }
    __syncthreads();
    unsigned short* out = slab + (size_t)blockIdx.x * PAGE;
    for (int i = threadIdx.x; i < PAGE; i += 256) out[i] = (unsigned short)hi[i];
}

// fold cnt: total per dest + per-block exclusive offsets written back in place (u16)
__global__ __launch_bounds__(256) void k_fold_cnt(unsigned short* __restrict__ slab, int* __restrict__ cnt, int N) {
    int i = blockIdx.x * 256 + threadIdx.x;
    if (i >= N) return;
    int p = i / PAGE, ld = i - p * PAGE;
    unsigned short* base = slab + (size_t)(p * BPP) * PAGE + ld;
    int run = 0;
#pragma unroll
    for (int b = 0; b < BPP; ++b) {
        size_t off = (size_t)b * PAGE;
        int v = base[off];
        base[off] = (unsigned short)run;
        run += v;
    }
    cnt[i] = run;
}

// ---- 3-kernel exclusive scan of cnt[N] -> rowp[N], chunk = 1024 ----
__global__ __launch_bounds__(256) void k_scanA(const int* __restrict__ cnt, int* __restrict__ csum, int N) {
    __shared__ int s[256];
    int t = threadIdx.x, base = blockIdx.x * 1024;
    int p = 0;
#pragma unroll
    for (int j = 0; j < 4; ++j) { int idx = base + t + 256 * j; if (idx < N) p += cnt[idx]; }
    s[t] = p; __syncthreads();
    for (int off = 128; off > 0; off >>= 1) { if (t < off) s[t] += s[t + off]; __syncthreads(); }
    if (t == 0) csum[blockIdx.x] = s[0];
}

__global__ __launch_bounds__(256) void k_scanB(int* __restrict__ csum, int NC) {
    __shared__ int s[256];
    int t = threadIdx.x;
    int v = (t < NC) ? csum[t] : 0;
    s[t] = v; __syncthreads();
    for (int off = 1; off < 256; off <<= 1) {
        int x = (t >= off) ? s[t - off] : 0;
        __syncthreads();
        s[t] += x; __syncthreads();
    }
    if (t < NC) csum[t] = s[t] - v;  // exclusive
}

__global__ __launch_bounds__(256) void k_scanC(const int* __restrict__ cnt, const int* __restrict__ csum,
                                               int* __restrict__ rowp, int N) {
    __shared__ int s[256];
    int t = threadIdx.x, base = blockIdx.x * 1024 + t * 4;
    int c0 = (base + 0 < N) ? cnt[base + 0] : 0;
    int c1 = (base + 1 < N) ? cnt[base + 1] : 0;
    int c2 = (base + 2 < N) ? cnt[base + 2] : 0;
    int c3 = (base + 3 < N) ? cnt[base + 3] : 0;
    int ts = c0 + c1 + c2 + c3;
    s[t] = ts; __syncthreads();
    for (int off = 1; off < 256; off <<= 1) {
        int x = (t >= off) ? s[t - off] : 0;
        __syncthreads();
        s[t] += x; __syncthreads();
    }
    int o = csum[blockIdx.x] + s[t] - ts;
    if (base + 0 < N) rowp[base + 0] = o;
    if (base + 1 < N) rowp[base + 1] = o + c0;
    if (base + 2 < N) rowp[base + 2] = o + c0 + c1;
    if (base + 3 < N) rowp[base + 3] = o + c0 + c1 + c2;
}

// ---- scatter: deterministic positions, LDS cursors only; packed 4B payload ----
// payload = (src << 15) | (bf16(dinv[src]*ew) & 0x7fff)   [w >= 0, src < 2^17]
__global__ __launch_bounds__(256) void k_scat(const int* __restrict__ row, const int* __restrict__ col,
                                              const float* __restrict__ ew, const float* __restrict__ dinv,
                                              const int* __restrict__ rowp, const unsigned short* __restrict__ slab,
                                              unsigned* __restrict__ srcw, int E, int chunk) {
    __shared__ int cur[PAGE];
    int p = blockIdx.x / BPP, b = blockIdx.x - p * BPP;
    int lo = p * PAGE;
    for (int i = threadIdx.x; i < PAGE; i += 256) cur[i] = 0;
    __syncthreads();
    const unsigned short* soff = slab + (size_t)blockIdx.x * PAGE;
    int e0 = b * chunk, e1 = min(e0 + chunk, E);
    int evec = e0 + ((e1 - e0) & ~3);
    for (int e = e0 + (int)threadIdx.x * 4; e + 4 <= evec; e += 1024) {
        int4 c4 = *(const int4*)(col + e);
        unsigned a = (unsigned)(c4.x - lo), bq = (unsigned)(c4.y - lo);
        unsigned cc = (unsigned)(c4.z - lo), dq = (unsigned)(c4.w - lo);
        if ((a < PAGE) | (bq < PAGE) | (cc < PAGE) | (dq < PAGE)) {
            int4 r4 = *(const int4*)(row + e);
            float4 w4 = *(const float4*)(ew + e);
            if (a < PAGE) {
                int pos = rowp[c4.x] + soff[a] + atomicAdd(&cur[a], 1);
                srcw[pos] = ((unsigned)r4.x << 15) | (bf_rne(dinv[r4.x] * w4.x) & 0x7fffu);
            }
            if (bq < PAGE) {
                int pos = rowp[c4.y] + soff[bq] + atomicAdd(&cur[bq], 1);
                srcw[pos] = ((unsigned)r4.y << 15) | (bf_rne(dinv[r4.y] * w4.y) & 0x7fffu);
            }
            if (cc < PAGE) {
                int pos = rowp[c4.z] + soff[cc] + atomicAdd(&cur[cc], 1);
                srcw[pos] = ((unsigned)r4.z << 15) | (bf_rne(dinv[r4.z] * w4.z) & 0x7fffu);
            }
            if (dq < PAGE) {
                int pos = rowp[c4.w] + soff[dq] + atomicAdd(&cur[dq], 1);
                srcw[pos] = ((unsigned)r4.w << 15) | (bf_rne(dinv[r4.w] * w4.w) & 0x7fffu);
            }
        }
    }
    for (int e = evec + (int)threadIdx.x; e < e1; e += 256) {
        int c = col[e];
        unsigned a = (unsigned)(c - lo);
        if (a < PAGE) {
            int r = row[e];
            int pos = rowp[c] + soff[a] + atomicAdd(&cur[a], 1);
            srcw[pos] = ((unsigned)r << 15) | (bf_rne(dinv[r] * ew[e]) & 0x7fffu);
        }
    }
}

// ---- weight -> MFMA fragment-order pack + bf16 hi/lo split ----
// F0[((ksg*4+t)*2+sel)*512 + lane*8 + j] = sel(hi/lo) of W0[k][n],
//   k = ksg*32 + (lane>>4)*8 + j, n = t*16 + (lane&15); ksg in [0,16).
// F1 same with ksg in [0,2). Consume load = base + lane*16B: fully coalesced.
__global__ __launch_bounds__(256) void k_wcvt(const float* __restrict__ W0, const float* __restrict__ W1,
                                              unsigned short* __restrict__ F0, unsigned short* __restrict__ F1) {
    int o = blockIdx.x * 256 + threadIdx.x;
    const float* W;
    unsigned short* F;
    int ksg, t, rem;
    if (o < 64 * 512) {          // layer 1: 64 frags of 512 u16
        int fragIdx = o >> 9;    // ksg*4 + t
        rem = o & 511;
        ksg = fragIdx >> 2; t = fragIdx & 3;
        W = W0; F = F0 + (size_t)(fragIdx * 2) * 512;
    } else {
        int o2 = o - 64 * 512;
        if (o2 >= 8 * 512) return;  // layer 2: 8 frags
        int fragIdx = o2 >> 9;
        rem = o2 & 511;
        ksg = fragIdx >> 2; t = fragIdx & 3;
        W = W1; F = F1 + (size_t)(fragIdx * 2) * 512;
    }
    int lane = rem >> 3, j = rem & 7;
    int k = ksg * 32 + (lane >> 4) * 8 + j;
    int n = t * 16 + (lane & 15);
    float v = W[(size_t)k * 64 + n];
    unsigned hi = bf_rne(v);
    float hv = __uint_as_float(hi << 16);
    unsigned lo = bf_rne(v - hv);
    F[rem] = (unsigned short)hi;        // sel=0
    F[512 + rem] = (unsigned short)lo;  // sel=1
}

// ---- MFMA 2-layer MLP: 64 rows/block, 4 waves, bf16 hi/lo split ----
// x staged per 128-k chunk (R10 wave-contiguous map), A-frags via ds_read_b128;
// W from fragment-packed global (coalesced 1KB/instr, L1-hot shared stream).
// D-frag: col = lane&15, row = 4*(lane>>4) + reg  [HW-verified].
__global__ __launch_bounds__(256, 4) void k_mlp(const float* __restrict__ x,
                                                const unsigned short* __restrict__ w0f,
                                                const unsigned short* __restrict__ w1f,
                                                const float* __restrict__ b0, const float* __restrict__ b1,
                                                unsigned* __restrict__ hb, int N) {
    __shared__ __align__(16) unsigned short xh[64 * XST];  // 17.4 KB: chunk A hi; layer-1 out reuses
    __shared__ __align__(16) unsigned short xl[64 * XST];  // 17.4 KB: chunk A lo
    int tid = threadIdx.x;
    int w = tid >> 6, lane = tid & 63;
    int g = lane >> 4, r16 = lane & 15;
    int rbase = blockIdx.x * 64;

    // stage map: instr i covers rows i*8 + (tid>>5), float4-col (tid&31): wave-contiguous
    int r8 = tid >> 5;   // 0..7
    int c4 = tid & 31;   // 0..31
    const float* xbase = x + (size_t)(rbase + r8) * 512 + c4 * 4;

    f32x4 acc[4];
#pragma unroll
    for (int t = 0; t < 4; ++t) acc[t] = (f32x4){0.f, 0.f, 0.f, 0.f};

    for (int kc = 0; kc < 4; ++kc) {  // 4 chunks of 128 k
        // ---- stage: load 8x float4, convert, write LDS ----
        float4 v[8];
#pragma unroll
        for (int i = 0; i < 8; ++i)
            v[i] = (rbase + i * 8 + r8 < N)
                       ? *(const float4*)(xbase + (size_t)i * 4096 + kc * 128)
                       : make_float4(0.f, 0.f, 0.f, 0.f);
#pragma unroll
        for (int i = 0; i < 8; ++i) {
            float e0 = v[i].x, e1 = v[i].y, e2 = v[i].z, e3 = v[i].w;
            unsigned u0 = __float_as_uint(e0), u1 = __float_as_uint(e1);
            unsigned u2 = __float_as_uint(e2), u3 = __float_as_uint(e3);
            // hi = truncate to bf16 (exact prefix), lo = rne(x - hi)
            unsigned short h0 = (unsigned short)(u0 >> 16), h1q = (unsigned short)(u1 >> 16);
            unsigned short h2 = (unsigned short)(u2 >> 16), h3 = (unsigned short)(u3 >> 16);
            float l0 = e0 - __uint_as_float(u0 & 0xffff0000u);
            float l1 = e1 - __uint_as_float(u1 & 0xffff0000u);
            float l2 = e2 - __uint_as_float(u2 & 0xffff0000u);
            float l3 = e3 - __uint_as_float(u3 & 0xffff0000u);
            int o = (i * 8 + r8) * XST + c4 * 4;
            *(ushort4*)(xh + o) = make_ushort4(h0, h1q, h2, h3);
            *(ushort4*)(xl + o) = make_ushort4((unsigned short)bf_rne(l0), (unsigned short)bf_rne(l1),
                                               (unsigned short)bf_rne(l2), (unsigned short)bf_rne(l3));
        }
        __syncthreads();
        // ---- consume: 4 MFMA k-steps of 32 ----
#pragma unroll
        for (int ks = 0; ks < 4; ++ks) {
            int kk = ks * 32 + g * 8;
            bf16x8 ah = *(const bf16x8*)(xh + (w * 16 + r16) * XST + kk);
            bf16x8 al = *(const bf16x8*)(xl + (w * 16 + r16) * XST + kk);
            int ksg = kc * 4 + ks;
#pragma unroll
            for (int t = 0; t < 4; ++t) {
                const unsigned short* wf = w0f + (size_t)((ksg * 4 + t) * 2) * 512 + lane * 8;
                bf16x8 wh = *(const bf16x8*)wf;
                bf16x8 wl = *(const bf16x8*)(wf + 512);
                acc[t] = __builtin_amdgcn_mfma_f32_16x16x32_bf16(ah, wh, acc[t], 0, 0, 0);
                acc[t] = __builtin_amdgcn_mfma_f32_16x16x32_bf16(al, wh, acc[t], 0, 0, 0);
                acc[t] = __builtin_amdgcn_mfma_f32_16x16x32_bf16(ah, wl, acc[t], 0, 0, 0);
            }
        }
        __syncthreads();  // before next chunk's staging overwrites LDS
    }
    // ---- epilogue L1: +b0, relu, hi/lo split -> LDS (row-stride 72) ----
#pragma unroll
    for (int t = 0; t < 4; ++t) {
        int c = t * 16 + r16;
        float bb = b0[c];
#pragma unroll
        for (int r = 0; r < 4; ++r) {
            float vv = fmaxf(acc[t][r] + bb, 0.f);
            unsigned u = __float_as_uint(vv);
            unsigned short hi = (unsigned short)(u >> 16);
            float lo = vv - __uint_as_float(u & 0xffff0000u);
            int rr = w * 16 + g * 4 + r;
            xh[rr * 72 + c] = hi;
            xl[rr * 72 + c] = (unsigned short)bf_rne(lo);
        }
    }
    __syncthreads();
    // ---- layer 2: K = 64, 2 k-steps ----
    f32x4 acc2[4];
#pragma unroll
    for (int t = 0; t < 4; ++t) acc2[t] = (f32x4){0.f, 0.f, 0.f, 0.f};
#pragma unroll
    for (int ks = 0; ks < 2; ++ks) {
        int k0 = ks * 32 + g * 8;
        bf16x8 ah = *(const bf16x8*)(xh + (w * 16 + r16) * 72 + k0);
        bf16x8 al = *(const bf16x8*)(xl + (w * 16 + r16) * 72 + k0);
#pragma unroll
        for (int t = 0; t < 4; ++t) {
            const unsigned short* wf = w1f + (size_t)((ks * 4 + t) * 2) * 512 + lane * 8;
            bf16x8 wh = *(const bf16x8*)wf;
            bf16x8 wl = *(const bf16x8*)(wf + 512);
            acc2[t] = __builtin_amdgcn_mfma_f32_16x16x32_bf16(ah, wh, acc2[t], 0, 0, 0);
            acc2[t] = __builtin_amdgcn_mfma_f32_16x16x32_bf16(al, wh, acc2[t], 0, 0, 0);
            acc2[t] = __builtin_amdgcn_mfma_f32_16x16x32_bf16(ah, wl, acc2[t], 0, 0, 0);
        }
    }
    // ---- epilogue L2: +b1 -> bf16 u16 stores ----
    unsigned short* hb16 = (unsigned short*)hb;
#pragma unroll
    for (int t = 0; t < 4; ++t) {
        int c = t * 16 + r16;
        float bb = b1[c];
#pragma unroll
        for (int r = 0; r < 4; ++r) {
            int grow = rbase + w * 16 + g * 4 + r;
            if (grow < N) {
                float vv = acc2[t][r] + bb;
                hb16[(size_t)grow * 64 + c] = (unsigned short)bf_rne(vv);
            }
        }
    }
}

// ---- propagation: wave per dest, 2 edges x 32 lanes, bf16 z gather, predicated unroll 8 ----
// srcw packed 4B: src = pk>>15, w = bits((pk&0x7fff)<<16); agg scaled by dinv[d] in epilogue.
__global__ __launch_bounds__(256) void k_prop(const unsigned* __restrict__ srcw,
                                              const int* __restrict__ rowp, const int* __restrict__ cnt,
                                              const float* __restrict__ dinv,
                                              const unsigned* __restrict__ zin, const unsigned* __restrict__ hb,
                                              unsigned* __restrict__ zout_b, float* __restrict__ zout_f, int N) {
    int wid = (blockIdx.x << 2) | (threadIdx.x >> 6);
    int d = __builtin_amdgcn_readfirstlane(wid);  // wave-uniform -> scalar loads for per-dest data
    if (d >= N) return;
    int lane = threadIdx.x & 63;
    int half = lane >> 5, fi = lane & 31;  // lane handles features (2fi, 2fi+1) of edge parity `half`
    int beg = rowp[d], end = beg + cnt[d];
    float ax = 0.f, ay = 0.f;
    for (int e = beg + half; e < end; e += 16) {  // 8 edges per parity always in flight
        unsigned pk[8];
#pragma unroll
        for (int k = 0; k < 8; ++k) {
            int idx = e + 2 * k;
            pk[k] = srcw[min(idx, end - 1)];  // clamp: dead slots re-read last valid edge (L1-hot)
        }
        unsigned z[8];
#pragma unroll
        for (int k = 0; k < 8; ++k) z[k] = zin[(pk[k] >> 15) * 32u + fi];
#pragma unroll
        for (int k = 0; k < 8; ++k) {
            float w = (e + 2 * k < end) ? __uint_as_float((pk[k] & 0x7fffu) << 16) : 0.f;
            ax = fmaf(w, bf_lo(z[k]), ax);
            ay = fmaf(w, bf_hi(z[k]), ay);
        }
    }
    ax += __shfl_xor(ax, 32);
    ay += __shfl_xor(ay, 32);
    if (half == 0) {
        float di = dinv[d];
        unsigned zs = zin[(size_t)d * 32 + fi];  // analytic self-loop
        float s2 = di * di;
        float ox = 0.9f * fmaf(di, ax, s2 * bf_lo(zs));
        float oy = 0.9f * fmaf(di, ay, s2 * bf_hi(zs));
        unsigned hz = hb[(size_t)d * 32 + fi];
        ox = fmaf(0.1f, bf_lo(hz), ox);
        oy = fmaf(0.1f, bf_hi(hz), oy);
        if (zout_f) ((float2*)zout_f)[(size_t)d * 32 + fi] = make_float2(ox, oy);
        else zout_b[(size_t)d * 32 + fi] = bf_pack(ox, oy);
    }
}

extern "C" void kernel_launch(void* const* d_in, const int* in_sizes, int n_in,
                              void* d_out, int out_size, void* d_ws, size_t ws_size,
                              hipStream_t stream) {
    const float* x  = (const float*)d_in[0];
    const int*   ei = (const int*)d_in[1];
    const float* ew = (const float*)d_in[2];
    const float* W0 = (const float*)d_in[3];
    const float* b0 = (const float*)d_in[4];
    const float* W1 = (const float*)d_in[5];
    const float* b1 = (const float*)d_in[6];
    int N = in_sizes[0] / 512;
    int E = in_sizes[2];
    const int* row = ei;
    const int* col = ei + E;

    char* p = (char*)d_ws;
    auto alloc = [&](size_t bytes) -> char* {
        char* r = p;
        p += (bytes + 255) & ~(size_t)255;
        return r;
    };
    int NPg = (N + PAGE - 1) / PAGE;                         // 7 pages for N=100K
    size_t zbytes = (size_t)N * 32 * 4;                      // 12.8 MB per bf16 z buffer
    size_t slab_bytes = (size_t)NPg * BPP * PAGE * 4;        // 28.9 MB float deg slab (hosts u16 cnt slab too)
    unsigned* hb  = (unsigned*)alloc(zbytes);                // bf16 h, persists all iters
    float* slabf  = (float*)alloc(slab_bytes);               // dead after k_scat
    unsigned* srcw = (unsigned*)alloc((size_t)E * 4);        // 12.8 MB packed edges
    float* dinv  = (float*)alloc((size_t)N * 4);
    int* cnt     = (int*)alloc((size_t)N * 4);
    int* rowp    = (int*)alloc((size_t)N * 4);
    int* csum    = (int*)alloc(512 * 4);
    unsigned short* w0f = (unsigned short*)alloc(64 * 2 * 512 * 2);  // W0 frag-packed hi/lo, 128 KB
    unsigned short* w1f = (unsigned short*)alloc(8 * 2 * 512 * 2);   // W1 frag-packed hi/lo, 16 KB
    unsigned short* slabu = (unsigned short*)slabf;  // sequential reuse: deg fold before k_cnt writes
    // zb0/zb1 overlay the slab region (slab dead once k_scat finishes; stream order).
    unsigned* zb0 = (unsigned*)slabf;
    unsigned* zb1 = (unsigned*)((char*)slabf + zbytes);

    int gN = (N + 255) / 256;
    int NC = (N + 1023) / 1024;
    int chunk = (((E + BPP - 1) / BPP) + 3) & ~3;
    int gridPg = NPg * BPP;

    k_wcvt<<<(64 * 512 + 8 * 512 + 255) / 256, 256, 0, stream>>>(W0, W1, w0f, w1f);
    k_deg<<<gridPg, 256, 0, stream>>>(row, ew, slabf, E, chunk);
    k_fold_deg<<<gN, 256, 0, stream>>>(slabf, dinv, N);
    k_cnt<<<gridPg, 256, 0, stream>>>(col, slabu, E, chunk);
    k_fold_cnt<<<gN, 256, 0, stream>>>(slabu, cnt, N);
    k_scanA<<<NC, 256, 0, stream>>>(cnt, csum, N);
    k_scanB<<<1, 256, 0, stream>>>(csum, NC);
    k_scanC<<<NC, 256, 0, stream>>>(cnt, csum, rowp, N);
    k_scat<<<gridPg, 256, 0, stream>>>(row, col, ew, dinv, rowp, slabu, srcw, E, chunk);
    k_mlp<<<(N + 63) / 64, 256, 0, stream>>>(x, w0f, w1f, b0, b1, hb, N);

    unsigned* zbufs[2] = { zb0, zb1 };  // iter it writes zbufs[it&1] (bf16) except final
    const unsigned* zi = hb;            // z0 = bf16(h), no conversion kernel needed
    int gP = (N + 3) / 4;
    for (int it = 0; it < 10; ++it) {
        if (it < 9) {
            unsigned* zo = zbufs[it & 1];
            k_prop<<<gP, 256, 0, stream>>>(srcw, rowp, cnt, dinv, zi, hb, zo, nullptr, N);
            zi = zo;
        } else {
            k_prop<<<gP, 256, 0, stream>>>(srcw, rowp, cnt, dinv, zi, hb, nullptr, (float*)d_out, N);
        }
    }
}